// Round 14
// baseline (679.705 us; speedup 1.0000x reference)
//
#include <hip/hip_runtime.h>

// ConeIntersection fused kernel for MI355X (gfx950).
// N=4, B=8192, DIM=1024, HEADS=4, HD=256. Device buffers FP32; comparison in
// bf16 domain (2% of max). Numerics byte-identical to passing r3/r8/r10
// kernels (2-term f16 RNE splits, 3 MFMAs/product axis path; plain f16 arg
// path; pre-scaled x16, scores /256).
//
// Round-14: M=128 tile, 1024 threads (16 waves, nt=1 col-tile/wave).
// r13's M=128 @512thr spilled (128 AGPR acc + ~100 VGPR > 256 budget ->
// WRITE_SIZE 303MB). Same tile at 1024 threads halves per-wave state:
// acc = 64 AGPR, dbuf weights = 24 VGPR, ~160 regs total -> no spill.
// Weight-L2 traffic: 1024 blocks x 1.15MB = 1.18GB (4x less than r10),
// 3 weight loads feed 32 MFMAs per kk per wave (self-hiding).
// LDS 144KB (1 block/CU; r11 showed 1 block/CU costs nothing).
// Tail global reads batched into register arrays before compute.

typedef __attribute__((ext_vector_type(8))) _Float16 f16x8;
typedef __attribute__((ext_vector_type(8))) float f32x8;
typedef __attribute__((ext_vector_type(4))) float f32x4;

#define BH 32768            // B*HEADS pairs
#define OUT_ARG_OFF 8388608 // B*DIM

// ws layout in halfs (fragment-linear within each array)
#define O_WXA_H 0
#define O_WXA_L 65536
#define O_WXR_H 131072
#define O_WXR_L 196608
#define O_WRA_H 262144
#define O_WRR_H 327680
#define O_W2X_H 393216
#define O_W2X_L 458752
#define O_W2G_H 524288
#define WS_HALFS 589824     // 1179648 bytes

__device__ __forceinline__ void split16(float x, _Float16& hi, _Float16& lo) {
  float xs = x * 16.0f;
  _Float16 h = (_Float16)xs;      // RNE
  hi = h;
  lo = (_Float16)(xs - (float)h); // residual; product error ~2^-22
}

// fragment-linear index for weights: element (col o, k) -> tile (o>>4, k>>5),
// lane ((k>>3)&3)*16 + (o&15), slot j=k&7.
__device__ __forceinline__ int fragidx(int o, int k) {
  int ct = o >> 4, kk = k >> 5, lg = (k >> 3) & 3, l15 = o & 15, j = k & 7;
  return (ct * 8 + kk) * 512 + (lg * 16 + l15) * 8 + j;
}

// ---- prep: combined + split layer weights (x16-scaled, frag-linear) ----
__global__ void combine_weights(const float* __restrict__ Wx1, const float* __restrict__ Wr1,
                                const float* __restrict__ W2x, const float* __restrict__ W2g,
                                _Float16* __restrict__ ws) {
  int i = blockIdx.x * 256 + threadIdx.x;  // 0..65535 ; o=i>>8, k=i&255
  int o = i >> 8, k = i & 255;
  int d = fragidx(o, k);
  float a = Wx1[o * 512 + k], b = Wx1[o * 512 + 256 + k];
  _Float16 h, l;
  split16(a + b, h, l);          ws[O_WXA_H + d] = h; ws[O_WXA_L + d] = l;
  split16(0.5f * (b - a), h, l); ws[O_WXR_H + d] = h; ws[O_WXR_L + d] = l;
  a = Wr1[o * 512 + k]; b = Wr1[o * 512 + 256 + k];
  ws[O_WRA_H + d] = (_Float16)((a + b) * 16.0f);
  ws[O_WRR_H + d] = (_Float16)((0.5f * (b - a)) * 16.0f);
  split16(W2x[o * 256 + k], h, l); ws[O_W2X_H + d] = h; ws[O_W2X_L + d] = l;
  ws[O_W2G_H + d] = (_Float16)(W2g[o * 256 + k] * 16.0f);
}

#define MFMA16 __builtin_amdgcn_mfma_f32_16x16x32_f16

// stage one fp32 operand (128 rows x 256 cols) -> split16 -> swizzled LDS
__device__ __forceinline__ void stage128(const float* __restrict__ src, int g0, int tid,
                                         _Float16* bufH, _Float16* bufL) {
  #pragma unroll
  for (int c = 0; c < 4; ++c) {
    const int i   = c * 1024 + tid;
    const int row = i >> 5;            // 0..127 ; n = row&3, pair = row>>2
    const int col = (i & 31) * 8;
    const int gofs = ((row & 3) * BH + g0 + (row >> 2)) * 256 + col;
    f32x8 v = *(const f32x8*)(src + gofs);
    f16x8 xh, xl;
    #pragma unroll
    for (int j = 0; j < 8; ++j) { _Float16 h, lo2; split16(v[j], h, lo2); xh[j] = h; xl[j] = lo2; }
    const int ad = row * 256 + (col ^ ((row & 7) << 3));
    *(f16x8*)(bufH + ad) = xh;
    *(f16x8*)(bufL + ad) = xl;
  }
}

// one GEMM1 operand pass (M=128, nt=1/wave): double-buffered weights.
__device__ __forceinline__ void gemm1_pass(const _Float16* __restrict__ ws,
                                           int oBh, int oBl, int oBm,
                                           const _Float16* bufH, const _Float16* bufL,
                                           int ct0, int l, int l15, int lg,
                                           f32x4 (&acc1)[8], f32x4 (&accm)[8]) {
  f16x8 wh[2], wl[2], wm[2];
  {
    const int fb = (ct0 << 3) * 512 + l * 8;
    wh[0] = *(const f16x8*)(ws + oBh + fb);
    wl[0] = *(const f16x8*)(ws + oBl + fb);
    wm[0] = *(const f16x8*)(ws + oBm + fb);
  }
  #pragma unroll
  for (int kk = 0; kk < 8; ++kk) {
    const int cur = kk & 1, nx = cur ^ 1;
    if (kk < 7) {
      const int fb = ((ct0 << 3) + kk + 1) * 512 + l * 8;
      wh[nx] = *(const f16x8*)(ws + oBh + fb);
      wl[nx] = *(const f16x8*)(ws + oBl + fb);
      wm[nx] = *(const f16x8*)(ws + oBm + fb);
    }
    #pragma unroll
    for (int grp = 0; grp < 2; ++grp) {
      f16x8 ah[4], al[4];
      #pragma unroll
      for (int q = 0; q < 4; ++q) {
        const int row = ((grp * 4 + q) << 4) + l15;
        const int ad  = row * 256 + (((kk << 5) + (lg << 3)) ^ ((row & 7) << 3));
        ah[q] = *(const f16x8*)(bufH + ad);
        al[q] = *(const f16x8*)(bufL + ad);
      }
      #pragma unroll
      for (int q = 0; q < 4; ++q) {
        const int mt = grp * 4 + q;
        acc1[mt] = MFMA16(ah[q], wh[cur], acc1[mt], 0, 0, 0);
        acc1[mt] = MFMA16(al[q], wh[cur], acc1[mt], 0, 0, 0);
        acc1[mt] = MFMA16(ah[q], wl[cur], acc1[mt], 0, 0, 0);
        accm[mt] = MFMA16(ah[q], wm[cur], accm[mt], 0, 0, 0);
      }
    }
  }
}

__global__ __launch_bounds__(1024, 2)
void cone_main(const float* __restrict__ axisF, const float* __restrict__ argF,
               const float* __restrict__ bx1, const float* __restrict__ br1,
               const float* __restrict__ bg2,
               const _Float16* __restrict__ ws, float* __restrict__ out)
{
  __shared__ __align__(16) _Float16 lds[73728];  // 144KB
  _Float16* bufH = lds;            // 128x256: axis hi -> arg hi -> h1h
  _Float16* bufL = lds + 32768;    // 128x256: axis lo -> arg lo -> h1l
  _Float16* h1m  = lds + 65536;    // 32x256: mean relu(h1_arg)

  const int tid = threadIdx.x;
  const int w   = tid >> 6;        // wave 0..15
  const int l   = tid & 63;
  const int l15 = l & 15;
  const int lg  = l >> 4;
  int bid = blockIdx.x;
  bid = ((bid & 7) << 7) + (bid >> 3);   // XCD swizzle (1024 % 8 == 0)
  const int g0 = bid << 5;               // 32 pairs/block
  const float s = 1.0f / 256.0f;
  const int ct0 = w;                     // this wave's col-tile (16 cols)

  f32x4 acc1[8], accm[8];
  #pragma unroll
  for (int mt = 0; mt < 8; ++mt) { acc1[mt] = (f32x4){0,0,0,0}; accm[mt] = (f32x4){0,0,0,0}; }

  // ---- phase A: stage axis, axis-operand pass ----
  stage128(axisF, g0, tid, bufH, bufL);
  __syncthreads();
  gemm1_pass(ws, O_WXA_H, O_WXA_L, O_WRA_H, bufH, bufL, ct0, l, l15, lg, acc1, accm);
  __syncthreads();

  // ---- phase B: stage arg into same buffers, arg-operand pass ----
  stage128(argF, g0, tid, bufH, bufL);
  __syncthreads();
  gemm1_pass(ws, O_WXR_H, O_WXR_L, O_WRR_H, bufH, bufL, ct0, l, l15, lg, acc1, accm);
  __syncthreads();

  // ---- epilogue 1: h1 (split) overlays bufH/bufL; h1m mean ----
  {
    const int c  = (w << 4) + l15;
    const float bvx = bx1[c];
    const float bvr = br1[c];
    #pragma unroll
    for (int mt = 0; mt < 8; ++mt) {
      #pragma unroll
      for (int r = 0; r < 4; ++r) {
        const int row = (mt << 4) + (lg << 2) + r;
        const float v = fmaxf(acc1[mt][r] * s + bvx, 0.f);
        _Float16 h, lo2; split16(v, h, lo2);
        const int ad = row * 256 + (c ^ ((row & 7) << 3));
        bufH[ad] = h; bufL[ad] = lo2;
      }
      const int p = (mt << 2) + lg;   // pair index 0..31
      float sm = 0.f;
      #pragma unroll
      for (int r = 0; r < 4; ++r) sm += fmaxf(accm[mt][r] * s + bvr, 0.f);
      h1m[p * 256 + (c ^ ((p & 7) << 3))] = (_Float16)(0.25f * sm * 16.0f);
    }
  }
  __syncthreads();

  // ---------- GEMM2 (attn logits, split) + gate (plain) ----------
  _Float16* h1h = bufH;
  _Float16* h1l = bufL;
  f32x4 acc2[8];
  f32x4 acc3[2];
  #pragma unroll
  for (int mt = 0; mt < 8; ++mt) acc2[mt] = (f32x4){0,0,0,0};
  acc3[0] = (f32x4){0,0,0,0}; acc3[1] = (f32x4){0,0,0,0};
  {
    f16x8 wh[2], wl[2], wg[2];
    {
      const int fb = (ct0 << 3) * 512 + l * 8;
      wh[0] = *(const f16x8*)(ws + O_W2X_H + fb);
      wl[0] = *(const f16x8*)(ws + O_W2X_L + fb);
      wg[0] = *(const f16x8*)(ws + O_W2G_H + fb);
    }
    #pragma unroll
    for (int kk = 0; kk < 8; ++kk) {
      const int cur = kk & 1, nx = cur ^ 1;
      if (kk < 7) {
        const int fb = ((ct0 << 3) + kk + 1) * 512 + l * 8;
        wh[nx] = *(const f16x8*)(ws + O_W2X_H + fb);
        wl[nx] = *(const f16x8*)(ws + O_W2X_L + fb);
        wg[nx] = *(const f16x8*)(ws + O_W2G_H + fb);
      }
      const int k0 = (kk << 5) + (lg << 3);
      #pragma unroll
      for (int grp = 0; grp < 2; ++grp) {
        f16x8 ah[4], al[4];
        #pragma unroll
        for (int q = 0; q < 4; ++q) {
          const int row = ((grp * 4 + q) << 4) + l15;
          const int ad  = row * 256 + (k0 ^ ((row & 7) << 3));
          ah[q] = *(const f16x8*)(h1h + ad);
          al[q] = *(const f16x8*)(h1l + ad);
        }
        #pragma unroll
        for (int q = 0; q < 4; ++q) {
          const int mt = grp * 4 + q;
          acc2[mt] = MFMA16(ah[q], wh[cur], acc2[mt], 0, 0, 0);
          acc2[mt] = MFMA16(al[q], wh[cur], acc2[mt], 0, 0, 0);
          acc2[mt] = MFMA16(ah[q], wl[cur], acc2[mt], 0, 0, 0);
        }
      }
      #pragma unroll
      for (int mt2 = 0; mt2 < 2; ++mt2) {
        const int row2 = (mt2 << 4) + l15;
        const f16x8 am = *(const f16x8*)(h1m + row2 * 256 + (k0 ^ ((row2 & 7) << 3)));
        acc3[mt2] = MFMA16(am, wg[cur], acc3[mt2], 0, 0, 0);
      }
    }
  }

  // ---- softmax over n (in-lane) + circular mean -> axis_out (fp32) ----
  // b_axis2 omitted: constant per column across n, cancels in softmax(axis=0).
  // Batch all axis re-reads first (32 independent loads pipeline).
  {
    const int c = (w << 4) + l15;
    float av[8][4];
    #pragma unroll
    for (int mt = 0; mt < 8; ++mt) {
      const int g = g0 + (mt << 2) + lg;
      #pragma unroll
      for (int r = 0; r < 4; ++r) av[mt][r] = axisF[(r * BH + g) * 256 + c];
    }
    #pragma unroll
    for (int mt = 0; mt < 8; ++mt) {
      float lv[4];
      #pragma unroll
      for (int r = 0; r < 4; ++r) lv[r] = acc2[mt][r] * s;
      const float mx = fmaxf(fmaxf(lv[0], lv[1]), fmaxf(lv[2], lv[3]));
      float e[4]; float sum = 0.f;
      #pragma unroll
      for (int r = 0; r < 4; ++r) { e[r] = __expf(lv[r] - mx); sum += e[r]; }
      const float inv = 1.f / sum;
      const int g = g0 + (mt << 2) + lg;
      float x = 0.f, y = 0.f;
      #pragma unroll
      for (int r = 0; r < 4; ++r) {
        float sn, cs2;
        __sincosf(av[mt][r], &sn, &cs2);
        const float at = e[r] * inv;
        x += at * cs2;
        y += at * sn;
      }
      if (fabsf(x) < 0.001f) x = 0.001f;
      out[g * 256 + c] = atan2f(y, x);
    }
  }

  // ---- sigmoid gate * min_n arg -> arg_out (fp32) ----
  {
    const int c = (w << 4) + l15;
    const float bgv = bg2[c];
    float ag[2][4][4];
    #pragma unroll
    for (int mt2 = 0; mt2 < 2; ++mt2)
      #pragma unroll
      for (int r = 0; r < 4; ++r) {
        const int g = g0 + (mt2 << 4) + (lg << 2) + r;
        #pragma unroll
        for (int n = 0; n < 4; ++n) ag[mt2][r][n] = argF[(n * BH + g) * 256 + c];
      }
    #pragma unroll
    for (int mt2 = 0; mt2 < 2; ++mt2)
      #pragma unroll
      for (int r = 0; r < 4; ++r) {
        const int g = g0 + (mt2 << 4) + (lg << 2) + r;
        const float gate = 1.f / (1.f + __expf(-(acc3[mt2][r] * s + bgv)));
        float mn = fminf(fminf(ag[mt2][r][0], ag[mt2][r][1]),
                         fminf(ag[mt2][r][2], ag[mt2][r][3]));
        out[OUT_ARG_OFF + g * 256 + c] = mn * gate;
      }
  }
}

extern "C" void kernel_launch(void* const* d_in, const int* in_sizes, int n_in,
                              void* d_out, int out_size, void* d_ws, size_t ws_size,
                              hipStream_t stream) {
  const float* axisF = (const float*)d_in[0];
  const float* argF  = (const float*)d_in[1];
  const float* Wx1   = (const float*)d_in[2];
  const float* bx1   = (const float*)d_in[3];
  const float* Wr1   = (const float*)d_in[4];
  const float* br1   = (const float*)d_in[5];
  const float* W2x   = (const float*)d_in[6];
  // d_in[7] = b_axis2: constant over n at fixed column -> cancels in softmax
  const float* W2g   = (const float*)d_in[8];
  const float* bg2   = (const float*)d_in[9];
  float* out = (float*)d_out;
  _Float16* ws = (_Float16*)d_ws;

  combine_weights<<<256, 256, 0, stream>>>(Wx1, Wr1, W2x, W2g, ws);
  cone_main<<<1024, 1024, 0, stream>>>(axisF, argF, bx1, br1, bg2, ws, out);
}

// Round 15
// 296.256 us; speedup vs baseline: 2.2943x; 2.2943x over previous
//
#include <hip/hip_runtime.h>

// ConeIntersection fused kernel for MI355X (gfx950).
// N=4, B=8192, DIM=1024, HEADS=4, HD=256. Device buffers FP32; comparison in
// bf16 domain (2% of max). Numerics equivalent to passing r3/r8/r10 kernels
// (2-term f16 RNE splits, 3 MFMAs/product axis path; plain f16 arg path;
// pre-scaled x16, scores /256). Accumulation grouping differs (K=16 steps vs
// K=32) -> +-1 ulp bf16.
//
// Round-15 = r10 structure with the big GEMMs on mfma_f32_32x32x16_f16:
//  - ~15% faster matrix pipe (m119), half the MFMA instructions, acc1/accm
//    shrink 64->32 AGPR -> compiler can pipeline weight loads deeper under
//    the 128-VGPR cap of launch_bounds(512,2) (empirically minBlocks
//    semantics: cap = 2048/(blocks*waves) -> r13/r14 spills explained).
//  - Gate GEMM stays 16x16x32 (h1m only 8 live rows).
//  - LDS XOR swizzle widened to (row&31)<<3 (32-row tiles were 4-way
//    conflicted at &7); h1m keeps (p&7) (16-row buffer).
//  - Tail global re-reads batched into registers (r14's good piece).
//  - Unchanged: 8 pairs/block, grid 4096 XCD-swizzled, fused reg staging,
//    fragment-linear weights in d_ws, launch_bounds(512,2).
//
// 32x32x16 fragment maps (A/B by analogy to verified 16x16x32; C/D verified
// m74/m101): A: row=l&31, k=st*16+(l>>5)*8+j. B: col=l&31, same k split.
// C/D: col=l&31, row=(reg&3)+8*(reg>>2)+4*(l>>5)  -> reg quad g holds pair
// p=2g+(l>>5), n=reg&3 (softmax-over-n stays in-lane).

typedef __attribute__((ext_vector_type(8))) _Float16 f16x8;
typedef __attribute__((ext_vector_type(8))) float f32x8;
typedef __attribute__((ext_vector_type(4))) float f32x4;
typedef __attribute__((ext_vector_type(16))) float f32x16;

#define BH 32768            // B*HEADS pairs
#define OUT_ARG_OFF 8388608 // B*DIM

// ws layout in halfs (fragment-linear within each array)
#define O_WXA_H 0
#define O_WXA_L 65536
#define O_WXR_H 131072
#define O_WXR_L 196608
#define O_WRA_H 262144
#define O_WRR_H 327680
#define O_W2X_H 393216
#define O_W2X_L 458752
#define O_W2G_H 524288
#define WS_HALFS 589824     // 1179648 bytes

__device__ __forceinline__ void split16(float x, _Float16& hi, _Float16& lo) {
  float xs = x * 16.0f;
  _Float16 h = (_Float16)xs;      // RNE
  hi = h;
  lo = (_Float16)(xs - (float)h); // residual; product error ~2^-22
}

// 16x16x32 fragment-linear (gate GEMM): lane ((k>>3)&3)*16+(o&15), slot k&7
__device__ __forceinline__ int fragidx16(int o, int k) {
  return ((o >> 4) * 8 + (k >> 5)) * 512 + ((((k >> 3) & 3) << 4) + (o & 15)) * 8 + (k & 7);
}
// 32x32x16 fragment-linear: tile o>>5, step k>>4; lane ((k>>3)&1)*32+(o&31)
__device__ __forceinline__ int fragidx32(int o, int k) {
  return ((o >> 5) * 16 + (k >> 4)) * 512 + ((((k >> 3) & 1) << 5) + (o & 31)) * 8 + (k & 7);
}

// ---- prep: combined + split layer weights (x16-scaled, frag-linear) ----
__global__ void combine_weights(const float* __restrict__ Wx1, const float* __restrict__ Wr1,
                                const float* __restrict__ W2x, const float* __restrict__ W2g,
                                _Float16* __restrict__ ws) {
  int i = blockIdx.x * 256 + threadIdx.x;  // 0..65535 ; o=i>>8, k=i&255
  int o = i >> 8, k = i & 255;
  int d = fragidx32(o, k);
  float a = Wx1[o * 512 + k], b = Wx1[o * 512 + 256 + k];
  _Float16 h, l;
  split16(a + b, h, l);          ws[O_WXA_H + d] = h; ws[O_WXA_L + d] = l;
  split16(0.5f * (b - a), h, l); ws[O_WXR_H + d] = h; ws[O_WXR_L + d] = l;
  a = Wr1[o * 512 + k]; b = Wr1[o * 512 + 256 + k];
  ws[O_WRA_H + d] = (_Float16)((a + b) * 16.0f);
  ws[O_WRR_H + d] = (_Float16)((0.5f * (b - a)) * 16.0f);
  split16(W2x[o * 256 + k], h, l); ws[O_W2X_H + d] = h; ws[O_W2X_L + d] = l;
  ws[O_W2G_H + fragidx16(o, k)] = (_Float16)(W2g[o * 256 + k] * 16.0f);
}

#define MFMA16 __builtin_amdgcn_mfma_f32_16x16x32_f16
#define MFMA32 __builtin_amdgcn_mfma_f32_32x32x16_f16

// one GEMM1 operand pass (32x32x16): operand hi/lo in LDS; dbuf weights.
__device__ __forceinline__ void gemm1_pass32(const _Float16* __restrict__ ws,
                                             int oBh, int oBl, int oBm,
                                             const _Float16* bufH, const _Float16* bufL,
                                             int w, int l,
                                             f32x16& acc1, f32x16& accm) {
  const int row = l & 31;
  const int hi8 = (l >> 5) << 3;
  f16x8 wh[2], wl[2], wm[2];
  {
    const int fb = (w * 16) * 512 + l * 8;
    wh[0] = *(const f16x8*)(ws + oBh + fb);
    wl[0] = *(const f16x8*)(ws + oBl + fb);
    wm[0] = *(const f16x8*)(ws + oBm + fb);
  }
  #pragma unroll
  for (int st = 0; st < 16; ++st) {
    const int cur = st & 1, nx = cur ^ 1;
    if (st < 15) {
      const int fb = (w * 16 + st + 1) * 512 + l * 8;
      wh[nx] = *(const f16x8*)(ws + oBh + fb);
      wl[nx] = *(const f16x8*)(ws + oBl + fb);
      wm[nx] = *(const f16x8*)(ws + oBm + fb);
    }
    const int ad = row * 256 + ((st * 16 + hi8) ^ ((row & 31) << 3));
    const f16x8 ah = *(const f16x8*)(bufH + ad);
    const f16x8 al = *(const f16x8*)(bufL + ad);
    acc1 = MFMA32(ah, wh[cur], acc1, 0, 0, 0);
    acc1 = MFMA32(al, wh[cur], acc1, 0, 0, 0);
    acc1 = MFMA32(ah, wl[cur], acc1, 0, 0, 0);
    accm = MFMA32(ah, wm[cur], accm, 0, 0, 0);
  }
}

__global__ __launch_bounds__(512, 2)
void cone_main(const float* __restrict__ axisF, const float* __restrict__ argF,
               const float* __restrict__ bx1, const float* __restrict__ br1,
               const float* __restrict__ bg2,
               const _Float16* __restrict__ ws, float* __restrict__ out)
{
  __shared__ __align__(16) _Float16 lds[32768];  // 64KB
  _Float16* bufAxH = lds;            // 32x256 axis hi  -> later h1h
  _Float16* bufAxL = lds + 8192;     // 32x256 axis lo  -> later h1l
  _Float16* bufArH = lds + 16384;    // 32x256 arg hi   -> later h1m (16x256)
  _Float16* bufArL = lds + 24576;    // 32x256 arg lo

  const int tid = threadIdx.x;
  const int w   = tid >> 6;          // wave 0..7; owns cols [w*32, w*32+32)
  const int l   = tid & 63;
  const int l15 = l & 15;
  const int lg  = l >> 4;
  const int l31 = l & 31;
  const int lh  = l >> 5;            // 0/1
  int bid = blockIdx.x;
  bid = ((bid & 7) << 9) + (bid >> 3);   // XCD swizzle (4096 % 8 == 0)
  const int g0 = bid << 3;               // 8 pairs/block
  const float s = 1.0f / 256.0f;

  // ---------- stage A tiles: fp32 global -> reg split16 -> swizzled LDS ----
  {
    #pragma unroll
    for (int c = 0; c < 2; ++c) {
      const int i   = c * 512 + tid;
      const int row = i >> 5;            // 0..31 ; n = row&3, pair = row>>2
      const int col = (i & 31) * 8;
      const int gofs = ((row & 3) * BH + g0 + (row >> 2)) * 256 + col;
      f32x8 va = *(const f32x8*)(axisF + gofs);
      f32x8 vr = *(const f32x8*)(argF + gofs);
      f16x8 xh, xl, rh, rl;
      #pragma unroll
      for (int j = 0; j < 8; ++j) {
        _Float16 h, lo2;
        split16(va[j], h, lo2); xh[j] = h; xl[j] = lo2;
        split16(vr[j], h, lo2); rh[j] = h; rl[j] = lo2;
      }
      const int ad = row * 256 + (col ^ ((row & 31) << 3));
      *(f16x8*)(bufAxH + ad) = xh;
      *(f16x8*)(bufAxL + ad) = xl;
      *(f16x8*)(bufArH + ad) = rh;
      *(f16x8*)(bufArL + ad) = rl;
    }
  }
  __syncthreads();

  // ---------- GEMM1: two operand passes, 32x32x16 ----------
  f32x16 acc1, accm;
  #pragma unroll
  for (int i = 0; i < 16; ++i) { acc1[i] = 0.f; accm[i] = 0.f; }

  gemm1_pass32(ws, O_WXA_H, O_WXA_L, O_WRA_H, bufAxH, bufAxL, w, l, acc1, accm);
  gemm1_pass32(ws, O_WXR_H, O_WXR_L, O_WRR_H, bufArH, bufArL, w, l, acc1, accm);
  __syncthreads();   // all waves done reading bufAx/bufAr

  // ---------- epilogue 1: h1 (split) -> LDS overlay; h1m mean -> LDS ----
  _Float16* h1h = bufAxH;   // 32x256
  _Float16* h1l = bufAxL;   // 32x256
  _Float16* h1m = bufArH;   // 16x256 (rows 8..15 zeroed)
  *(unsigned long long*)&h1m[2048 + tid * 4] = 0ull;
  {
    const int c = (w << 5) + l31;
    const float bvx = bx1[c];
    const float bvr = br1[c];
    #pragma unroll
    for (int g = 0; g < 4; ++g) {
      float sm = 0.f;
      #pragma unroll
      for (int n = 0; n < 4; ++n) {
        const int r = g * 4 + n;
        const int row = (r & 3) + 8 * (r >> 2) + 4 * lh;  // = pair*4 + n
        const float v = fmaxf(acc1[r] * s + bvx, 0.f);
        _Float16 h, lo2; split16(v, h, lo2);
        const int ad = row * 256 + (c ^ ((row & 31) << 3));
        h1h[ad] = h; h1l[ad] = lo2;
        sm += fmaxf(accm[r] * s + bvr, 0.f);
      }
      const int p = 2 * g + lh;   // pair index 0..7
      h1m[p * 256 + (c ^ ((p & 7) << 3))] = (_Float16)(0.25f * sm * 16.0f);
    }
  }
  __syncthreads();

  // ---------- GEMM2 (attn logits, split, 32x32x16) ----------
  f32x16 acc2;
  #pragma unroll
  for (int i = 0; i < 16; ++i) acc2[i] = 0.f;
  {
    const int row = l31;
    const int hi8 = lh << 3;
    f16x8 w2h[2], w2l[2];
    {
      const int fb = (w * 16) * 512 + l * 8;
      w2h[0] = *(const f16x8*)(ws + O_W2X_H + fb);
      w2l[0] = *(const f16x8*)(ws + O_W2X_L + fb);
    }
    #pragma unroll
    for (int st = 0; st < 16; ++st) {
      const int cur = st & 1, nx = cur ^ 1;
      if (st < 15) {
        const int fb = (w * 16 + st + 1) * 512 + l * 8;
        w2h[nx] = *(const f16x8*)(ws + O_W2X_H + fb);
        w2l[nx] = *(const f16x8*)(ws + O_W2X_L + fb);
      }
      const int ad = row * 256 + ((st * 16 + hi8) ^ ((row & 31) << 3));
      const f16x8 ah = *(const f16x8*)(h1h + ad);
      const f16x8 al = *(const f16x8*)(h1l + ad);
      acc2 = MFMA32(ah, w2h[cur], acc2, 0, 0, 0);
      acc2 = MFMA32(al, w2h[cur], acc2, 0, 0, 0);
      acc2 = MFMA32(ah, w2l[cur], acc2, 0, 0, 0);
    }
  }

  // ---------- gate GEMM (16x16x32, h1m 16 rows) ----------
  f32x4 acc3[2];
  acc3[0] = (f32x4){0, 0, 0, 0}; acc3[1] = (f32x4){0, 0, 0, 0};
  {
    f16x8 wg[2][2];
    #pragma unroll
    for (int nt = 0; nt < 2; ++nt)
      wg[0][nt] = *(const f16x8*)(ws + O_W2G_H + (((w << 1) + nt) << 3) * 512 + l * 8);
    #pragma unroll
    for (int kk = 0; kk < 8; ++kk) {
      const int cur = kk & 1, nx = cur ^ 1;
      if (kk < 7) {
        #pragma unroll
        for (int nt = 0; nt < 2; ++nt)
          wg[nx][nt] = *(const f16x8*)(ws + O_W2G_H + ((((w << 1) + nt) << 3) + kk + 1) * 512 + l * 8);
      }
      const int k0 = (kk << 5) + (lg << 3);
      const f16x8 am = *(const f16x8*)&h1m[l15 * 256 + (k0 ^ ((l15 & 7) << 3))];
      acc3[0] = MFMA16(am, wg[cur][0], acc3[0], 0, 0, 0);
      acc3[1] = MFMA16(am, wg[cur][1], acc3[1], 0, 0, 0);
    }
  }

  // ---- softmax over n (in-lane reg quads) + circular mean -> axis_out ----
  // b_axis2 omitted: constant per column across n, cancels in softmax(axis=0).
  {
    const int c = (w << 5) + l31;
    float av[4][4];
    #pragma unroll
    for (int g = 0; g < 4; ++g) {
      const int gi = g0 + 2 * g + lh;
      #pragma unroll
      for (int n = 0; n < 4; ++n) av[g][n] = axisF[(n * BH + gi) * 256 + c];
    }
    #pragma unroll
    for (int g = 0; g < 4; ++g) {
      float lv[4];
      #pragma unroll
      for (int n = 0; n < 4; ++n) lv[n] = acc2[g * 4 + n] * s;
      const float mx = fmaxf(fmaxf(lv[0], lv[1]), fmaxf(lv[2], lv[3]));
      float e[4]; float sum = 0.f;
      #pragma unroll
      for (int n = 0; n < 4; ++n) { e[n] = __expf(lv[n] - mx); sum += e[n]; }
      const float inv = 1.f / sum;
      float x = 0.f, y = 0.f;
      #pragma unroll
      for (int n = 0; n < 4; ++n) {
        float sn, cs2;
        __sincosf(av[g][n], &sn, &cs2);
        const float at = e[n] * inv;
        x += at * cs2;
        y += at * sn;
      }
      if (fabsf(x) < 0.001f) x = 0.001f;
      const int gi = g0 + 2 * g + lh;
      out[gi * 256 + c] = atan2f(y, x);   // == arctan+quadrant correction
    }
  }

  // ---- sigmoid gate * min_n arg -> arg_out (fp32) ----
  {
    #pragma unroll
    for (int nt = 0; nt < 2; ++nt) {
      const int c = (w << 5) + (nt << 4) + l15;
      const float bgv = bg2[c];
      float ag[4][4];
      #pragma unroll
      for (int r = 0; r < 4; ++r) {
        const int p = (lg << 2) + r;
        if (p < 8) {
          const int gi = g0 + p;
          #pragma unroll
          for (int n = 0; n < 4; ++n) ag[r][n] = argF[(n * BH + gi) * 256 + c];
        }
      }
      #pragma unroll
      for (int r = 0; r < 4; ++r) {
        const int p = (lg << 2) + r;   // gate C row = pair index; only 0..7 live
        if (p < 8) {
          const int gi = g0 + p;
          const float gate = 1.f / (1.f + __expf(-(acc3[nt][r] * s + bgv)));
          const float mn = fminf(fminf(ag[r][0], ag[r][1]), fminf(ag[r][2], ag[r][3]));
          out[OUT_ARG_OFF + gi * 256 + c] = mn * gate;
        }
      }
    }
  }
}

extern "C" void kernel_launch(void* const* d_in, const int* in_sizes, int n_in,
                              void* d_out, int out_size, void* d_ws, size_t ws_size,
                              hipStream_t stream) {
  const float* axisF = (const float*)d_in[0];
  const float* argF  = (const float*)d_in[1];
  const float* Wx1   = (const float*)d_in[2];
  const float* bx1   = (const float*)d_in[3];
  const float* Wr1   = (const float*)d_in[4];
  const float* br1   = (const float*)d_in[5];
  const float* W2x   = (const float*)d_in[6];
  // d_in[7] = b_axis2: constant over n at fixed column -> cancels in softmax
  const float* W2g   = (const float*)d_in[8];
  const float* bg2   = (const float*)d_in[9];
  float* out = (float*)d_out;
  _Float16* ws = (_Float16*)d_ws;

  combine_weights<<<256, 256, 0, stream>>>(Wx1, Wr1, W2x, W2g, ws);
  cone_main<<<4096, 512, 0, stream>>>(axisF, argF, bx1, br1, bg2, ws, out);
}